// Round 4
// baseline (613.594 us; speedup 1.0000x reference)
//
#include <hip/hip_runtime.h>
#include <hip/hip_bf16.h>
#include <hip/hip_cooperative_groups.h>

namespace cg = cooperative_groups;

#define NROW 327680            // 256*256*5
#define NCLS 80
#define K_TARGET 1024u
#define CAP 2048u              // == MAXN
#define MAXN 2048
#define MAX_OUT 100
#define NBIN 864               // score in (0.01,1): bits>>16 in [0x3C23, 0x3F80)
#define BIN0 0x3C23
#define HIST_BLOCKS 80
#define ADJW 32                // 2048 bits = 32 ull per adjacency row
#define ADJC_ROWS 128          // adjacency rows cached in LDS for the greedy scan
#define MGRID 512              // cooperative grid: 2 blocks/CU guaranteed resident

// ---------------- workspace layout (bytes) ----------------
// (legacy layout kept below for the fallback path; mega uses the same names)
#define WS_SCORES 0            // float[NROW]              1,310,720
#define WS_PART   1310720      // uint[MGRID*NBIN]         1,769,472
#define WS_COLSUM 3080192      // uint[NBIN] (pad 4096)        4,096
#define WS_CNT    3084288      // uint[16]                        64
#define WS_KEPT   3084352      // int[128] knum+kept[100]        512
#define WS_KEYS   3084864      // ull[MAXN]                   16,384
#define WS_SORT   3101248      // ull[MAXN]                   16,384
#define WS_CBOX   3117632      // float4[MAXN]                32,768
#define WS_ADJ    3150400      // ull[MAXN*ADJW]             524,288

typedef float f4v __attribute__((ext_vector_type(4)));
typedef f4v f4u __attribute__((aligned(4)));   // 4B-aligned float4 load
typedef unsigned long long ull;

// ===========================================================================
// R4: single cooperative mega-kernel. Rationale: R0/R1/R3 showed decode is
// invariant ~62-66us under three different access/occupancy structures
// (pattern-independent ~1.8 TB/s effective ceiling), while the per-iteration
// budget has ~80us of inter-dispatch gaps (7 kernels + fill ~= 155us of
// dispatches vs 236us total). This replaces 6 dispatch gaps with 7 grid.sync()
// and fuses hist into decode. Score math is the R0 register-resident code
// VERBATIM -> bit-identical scores; integer atomics for hist are exact;
// compact order normalized by rank sort -> outputs bit-identical.
// ===========================================================================
__global__ __launch_bounds__(256, 2) void mega_kernel(
    const float* __restrict__ x, const float* __restrict__ anchors,
    float* __restrict__ out,
    float* __restrict__ scores, unsigned* __restrict__ part,
    unsigned* __restrict__ colsum, unsigned* __restrict__ cnt,
    int* __restrict__ keptg, ull* __restrict__ keys,
    ull* __restrict__ sorted, float4* __restrict__ cboxg,
    ull* __restrict__ adj) {
  cg::grid_group grid = cg::this_grid();

  union SMem {                     // ~49.6 KB union -> 3 blocks/CU by LDS
    unsigned h[NBIN];
    struct { unsigned A[1024]; unsigned Bb[1024]; } scan;
    ull lk[MAXN];
    struct {
      ull sk[MAXN];                // 16 KB
      ull adjc[ADJC_ROWS * ADJW];  // 32 KB
      int keptcc[MAX_OUT];
    } fin;
  };
  __shared__ SMem sm;
  __shared__ unsigned blocal, bbase;
  __shared__ int knum_s;

  const int t = threadIdx.x;
  const int B = blockIdx.x;

  // ---------------- P0: decode + fused histogram ----------------
  for (int i = t; i < NBIN; i += 256) sm.h[i] = 0;
  if (B == 0) {                    // zero colsum/cnt before S1 (atomics in P1)
    for (int i = t; i < NBIN; i += 256) colsum[i] = 0;
    if (t < 16) cnt[t] = 0;
  }
  __syncthreads();

  for (int chunk = B; chunk < NROW / 256; chunk += MGRID) {
    const int r = chunk * 256 + t;
    const float* rp = x + (size_t)r * 85;

    float conf_l = rp[4];
    float cl[80];
    #pragma unroll
    for (int c = 0; c < 20; ++c) {           // floats 5..84 = exactly 20 x vec4
      f4v t4 = *(const f4u*)(rp + 5 + 4 * c);
      cl[4*c+0] = t4.x; cl[4*c+1] = t4.y; cl[4*c+2] = t4.z; cl[4*c+3] = t4.w;
    }
    float m = cl[0];
    #pragma unroll
    for (int c = 1; c < NCLS; ++c) { float l = cl[c]; if (l > m) m = l; }
    float s = 0.f;
    #pragma unroll
    for (int c = 0; c < NCLS; ++c) s += expf(cl[c] - m);
    float conf = 1.f / (1.f + expf(-conf_l));
    float best = conf * (1.f / s);
    float sval = (best > 0.01f) ? best : 0.f;
    scores[r] = sval;

    if (sval > 0.f) {
      int idx = (int)(__float_as_uint(sval) >> 16) - BIN0;
      if (idx > NBIN - 1) idx = NBIN - 1;
      atomicAdd(&sm.h[idx], 1u);             // LDS atomic only
    }
  }
  __syncthreads();
  for (int b = t; b < NBIN; b += 256) part[(size_t)B * NBIN + b] = sm.h[b];
  grid.sync();   // S1

  // ---------------- P1: reduce part -> colsum (seg-parallel, int atomics) ----
  {
    const int u = B * 256 + t;               // 6912 units = 864 bins x 8 segs
    if (u < NBIN * 8) {
      const int b = u >> 3, seg = u & 7;
      unsigned s0 = 0, s1 = 0, s2 = 0, s3 = 0;
      #pragma unroll
      for (int g = seg * 64; g < seg * 64 + 64; g += 4) {
        s0 += part[(size_t)(g + 0) * NBIN + b];
        s1 += part[(size_t)(g + 1) * NBIN + b];
        s2 += part[(size_t)(g + 2) * NBIN + b];
        s3 += part[(size_t)(g + 3) * NBIN + b];
      }
      atomicAdd(&colsum[b], s0 + s1 + s2 + s3);
    }
  }
  grid.sync();   // S2

  // ---------------- P2: suffix-scan -> threshold T (block 0) ----------------
  if (B == 0) {
    #pragma unroll
    for (int e = 0; e < 4; ++e) {
      int i = t + 256 * e;
      sm.scan.A[i] = (i < NBIN) ? colsum[i] : 0u;
    }
    __syncthreads();
    unsigned* src = sm.scan.A; unsigned* dst = sm.scan.Bb;
    for (int d = 1; d < 1024; d <<= 1) {
      #pragma unroll
      for (int e = 0; e < 4; ++e) {
        int i = t + 256 * e;
        dst[i] = src[i] + ((i + d < 1024) ? src[i + d] : 0u);
      }
      __syncthreads();
      unsigned* tmp = src; src = dst; dst = tmp;
    }
    #pragma unroll
    for (int e = 0; e < 4; ++e) {
      int i = t + 256 * e;
      if (src[i] >= K_TARGET && (i == 1023 || src[i + 1] < K_TARGET)) {
        unsigned T = (unsigned)i;
        if (src[i] > CAP) T += 1;            // residual sfx[i+1] < K_TARGET <= CAP
        cnt[1] = T;
      }
    }
    if (t == 0) {
      if (src[0] < K_TARGET) cnt[1] = 0;     // fewer than K positives: take all
      cnt[0] = 0;
    }
  }
  grid.sync();   // S3

  // ---------------- P3: compact (grid-stride; semantics == legacy) ----------
  {
    const unsigned Tthr = cnt[1];
    for (int chunk = B; chunk < NROW / 1024; chunk += MGRID) {
      if (t == 0) blocal = 0;
      __syncthreads();
      const int gi = chunk * 256 + t;
      float4 s4 = ((const float4*)scores)[gi];
      float sv[4] = {s4.x, s4.y, s4.z, s4.w};
      ull lkk[4]; int nl = 0;
      #pragma unroll
      for (int k = 0; k < 4; ++k) {
        float s = sv[k];
        if (s <= 0.f) continue;
        unsigned bits = __float_as_uint(s);
        int idx = (int)(bits >> 16) - BIN0;
        if (idx > NBIN - 1) idx = NBIN - 1;
        if ((unsigned)idx < Tthr) continue;
        unsigned r = (unsigned)(gi * 4 + k);
        lkk[nl++] = ((ull)bits << 32) | (ull)(0xFFFFFFFFu - r);
      }
      unsigned lpos = nl ? atomicAdd(&blocal, (unsigned)nl) : 0u;
      __syncthreads();
      if (t == 0 && blocal) bbase = atomicAdd(&cnt[0], blocal);
      __syncthreads();
      if (nl) {
        unsigned base = bbase + lpos;
        for (int i = 0; i < nl; ++i)
          if (base + i < CAP) keys[base + i] = lkk[i];
      }
      __syncthreads();
    }
  }
  grid.sync();   // S4

  unsigned n = cnt[0]; if (n > CAP) n = CAP;

  // ---------------- P4: rank-scatter sort + box decode (blocks 0..7) --------
  if (B < 8) {
    for (unsigned i = t; i < n; i += 256) sm.lk[i] = keys[i];
    __syncthreads();
    const unsigned i = (unsigned)(B * 256 + t);
    if (i < n) {
      const ull ki = sm.lk[i];
      unsigned rank = 0;
      #pragma unroll 4
      for (unsigned j = 0; j < n; ++j) rank += (sm.lk[j] > ki) ? 1u : 0u;

      sorted[rank] = ki;

      unsigned r = 0xFFFFFFFFu - (unsigned)(ki & 0xFFFFFFFFull);
      const float* rp = x + (size_t)r * 85;
      float tx = rp[0], ty = rp[1], tw = rp[2], th = rp[3];
      const int a  = (int)(r % 5u);
      const int hw = (int)(r / 5u);
      const float wf = (float)(hw & 255);
      const float hf = (float)(hw >> 8);
      float sx = 1.f / (1.f + expf(-tx));
      float sy = 1.f / (1.f + expf(-ty));
      float xc = (sx + wf) / 256.f;
      float yc = (sy + hf) / 256.f;
      float bw = expf(tw) * anchors[2*a]     / 256.f;
      float bh = expf(th) * anchors[2*a + 1] / 256.f;
      float hwd = bw / 2.f, hhd = bh / 2.f;
      cboxg[rank] = make_float4(xc - hwd, yc - hhd, xc + hwd, yc + hhd);
    }
  }
  grid.sync();   // S5

  // ---------------- P5: adjacency bitmap (grid-stride rows) -----------------
  for (unsigned i = B; i < n; i += MGRID) {
    const float4 bi = cboxg[i];
    const float areai = (bi.z - bi.x) * (bi.w - bi.y);
    const int wid = t >> 6, lane = t & 63;
    #pragma unroll
    for (int pass = 0; pass < 8; ++pass) {
      unsigned j = (unsigned)(pass * 256 + t);
      bool sup = false;
      if (j < n) {
        float4 bj = cboxg[j];
        float xx1 = fmaxf(bi.x, bj.x), yy1 = fmaxf(bi.y, bj.y);
        float xx2 = fminf(bi.z, bj.z), yy2 = fminf(bi.w, bj.w);
        float inter = fmaxf(xx2 - xx1, 0.f) * fmaxf(yy2 - yy1, 0.f);
        float areaj = (bj.z - bj.x) * (bj.w - bj.y);
        float uni = areai + areaj - inter;
        float iou = (uni > 0.f) ? (inter / uni) : 0.f;
        sup = iou > 0.5f;
      }
      ull m = __ballot(sup);
      if (lane == 0) adj[(size_t)i * ADJW + pass * 4 + wid] = m;
    }
  }
  grid.sync();   // S6

  // ---------------- P6: greedy bitmask scan (block 0) -----------------------
  if (B == 0) {
    for (unsigned i = t; i < n; i += 256) sm.fin.sk[i] = sorted[i];
    const unsigned ncache = (n < ADJC_ROWS ? n : ADJC_ROWS) * ADJW;
    for (unsigned i = t; i < ncache; i += 256) sm.fin.adjc[i] = adj[i];
    if (t == 0) knum_s = 0;
    __syncthreads();

    if (t < 64) {
      const int lane = t;
      ull mask = 0ull;
      int nk = 0;
      ull rA = 0ull, rB = 0ull;
      if (lane < ADJW) {
        if (n > 0) rA = sm.fin.adjc[0 * ADJW + lane];
        if (n > 1) rB = (1 < ADJC_ROWS) ? sm.fin.adjc[1 * ADJW + lane]
                                        : adj[1 * ADJW + lane];
      }
      for (unsigned cc = 0; cc < n; ++cc) {
        ull rC = 0ull;
        unsigned pcc = cc + 2;
        if (lane < ADJW && pcc < n)
          rC = (pcc < ADJC_ROWS) ? sm.fin.adjc[pcc * ADJW + lane]
                                 : adj[(size_t)pcc * ADJW + lane];
        const int w = (int)(cc >> 6);
        ull mw = (ull)__shfl((long long)mask, w, 64);
        bool sup = (mw >> (cc & 63u)) & 1ull;
        if (!sup) {
          mask |= rA;                         // row cc (self bit harmless)
          if (lane == 0) sm.fin.keptcc[nk] = (int)cc;
          ++nk;
          if (nk == MAX_OUT) break;
        }
        rA = rB; rB = rC;
      }
      if (lane == 0) knum_s = nk;
    }
    __syncthreads();
    if (t == 0) keptg[0] = knum_s;
    if (t < MAX_OUT) keptg[1 + t] = (t < knum_s) ? sm.fin.keptcc[t] : -1;
  }
  grid.sync();   // S7

  // ---------------- P7: class argmax + outputs (blocks 0..99) ---------------
  if (B < MAX_OUT) {
    const int kn = keptg[0];
    const int cc = (B < kn) ? keptg[1 + B] : -1;
    if (cc >= 0) {
      const ull key = sorted[cc];
      const unsigned r = 0xFFFFFFFFu - (unsigned)(key & 0xFFFFFFFFull);
      if (t < 64) {
        const int lane = t;
        const float* rp = x + (size_t)r * 85;
        float l0 = rp[5 + lane];
        unsigned b0 = __float_as_uint(l0);
        b0 = (b0 & 0x80000000u) ? ~b0 : (b0 | 0x80000000u);
        ull kv = ((ull)b0 << 32) | (ull)(0xFFFFFFFFu - lane);
        if (lane < 16) {
          float l1 = rp[5 + 64 + lane];
          unsigned b1 = __float_as_uint(l1);
          b1 = (b1 & 0x80000000u) ? ~b1 : (b1 | 0x80000000u);
          ull kv1 = ((ull)b1 << 32) | (ull)(0xFFFFFFFFu - (64 + lane));
          if (kv1 > kv) kv = kv1;
        }
        #pragma unroll
        for (int d = 32; d >= 1; d >>= 1) {
          ull o = (ull)__shfl_xor((long long)kv, d, 64);
          if (o > kv) kv = o;
        }
        if (lane == 0)
          out[500 + B] = (float)(int)(0xFFFFFFFFu - (unsigned)(kv & 0xFFFFFFFFull));
      }
      if (t == 0) {
        out[B] = __uint_as_float((unsigned)(key >> 32));
        ((float4*)(out + 100))[B] = cboxg[cc];
      }
    } else {
      if (t == 0) {
        out[B] = 0.f;
        ((float4*)(out + 100))[B] = make_float4(0.f, 0.f, 0.f, 0.f);
        out[500 + B] = -1.f;
      }
    }
  }
}

// ===========================================================================
// Legacy 7-kernel path (R3, proven 236us / absmax 0.0) — fallback if the
// cooperative launch is rejected at enqueue.
// ===========================================================================
__global__ __launch_bounds__(256, 5) void decode_score(
    const float* __restrict__ x, float* __restrict__ scores) {
  __shared__ float sc[24][256];
  const int t = threadIdx.x;
  const int r = blockIdx.x * 256 + t;
  const float* rp = x + (size_t)r * 85;

  float conf_l = rp[4];
  float cl[56];
  #pragma unroll
  for (int k = 0; k < 14; ++k) {
    f4v t4 = *(const f4u*)(rp + 5 + 4 * k);
    cl[4*k+0] = t4.x; cl[4*k+1] = t4.y; cl[4*k+2] = t4.z; cl[4*k+3] = t4.w;
  }
  #pragma unroll
  for (int k = 14; k < 20; ++k) {
    f4v t4 = *(const f4u*)(rp + 5 + 4 * k);
    sc[4*(k-14)+0][t] = t4.x; sc[4*(k-14)+1][t] = t4.y;
    sc[4*(k-14)+2][t] = t4.z; sc[4*(k-14)+3][t] = t4.w;
  }
  float m = cl[0];
  #pragma unroll
  for (int c = 1; c < 56; ++c) { float l = cl[c]; if (l > m) m = l; }
  #pragma unroll
  for (int c = 56; c < 80; ++c) { float l = sc[c-56][t]; if (l > m) m = l; }
  float s = 0.f;
  #pragma unroll
  for (int c = 0; c < 56; ++c) s += expf(cl[c] - m);
  #pragma unroll
  for (int c = 56; c < 80; ++c) s += expf(sc[c-56][t] - m);
  float conf = 1.f / (1.f + expf(-conf_l));
  float best = conf * (1.f / s);
  scores[r] = (best > 0.01f) ? best : 0.f;
}

__global__ __launch_bounds__(1024) void hist_kernel(
    const float* __restrict__ scores, unsigned* __restrict__ part) {
  __shared__ unsigned h[NBIN];
  const int t = threadIdx.x;
  if (t < NBIN) h[t] = 0;
  __syncthreads();
  float4 s4 = ((const float4*)scores)[blockIdx.x * 1024 + t];
  float sv[4] = {s4.x, s4.y, s4.z, s4.w};
  #pragma unroll
  for (int k = 0; k < 4; ++k) {
    float s = sv[k];
    if (s > 0.f) {
      int idx = (int)(__float_as_uint(s) >> 16) - BIN0;
      if (idx > NBIN - 1) idx = NBIN - 1;
      atomicAdd(&h[idx], 1u);
    }
  }
  __syncthreads();
  if (t < NBIN) part[blockIdx.x * NBIN + t] = h[t];
}

__global__ __launch_bounds__(1024) void thresh_kernel(
    const unsigned* __restrict__ part, unsigned* __restrict__ cnt) {
  __shared__ unsigned bufA[1024], bufB[1024];
  const int t = threadIdx.x;
  unsigned colsum = 0;
  if (t < NBIN) {
    unsigned a0 = 0, a1 = 0, a2 = 0, a3 = 0;
    #pragma unroll
    for (int b = 0; b < HIST_BLOCKS; b += 4) {
      a0 += part[(b + 0) * NBIN + t];
      a1 += part[(b + 1) * NBIN + t];
      a2 += part[(b + 2) * NBIN + t];
      a3 += part[(b + 3) * NBIN + t];
    }
    colsum = a0 + a1 + a2 + a3;
  }
  bufA[t] = colsum;
  __syncthreads();
  unsigned* src = bufA; unsigned* dst = bufB;
  for (int d = 1; d < 1024; d <<= 1) {
    unsigned val = src[t] + ((t + d < 1024) ? src[t + d] : 0u);
    dst[t] = val;
    __syncthreads();
    unsigned* tmp = src; src = dst; dst = tmp;
  }
  if (src[t] >= K_TARGET && (t == 1023 || src[t + 1] < K_TARGET)) {
    unsigned T = (unsigned)t;
    if (src[t] > CAP) T += 1;
    cnt[1] = T;
  }
  if (t == 0) {
    if (src[0] < K_TARGET) cnt[1] = 0;
    cnt[0] = 0;
  }
}

__global__ __launch_bounds__(256) void compact_kernel(
    const float* __restrict__ scores, unsigned* __restrict__ cnt,
    ull* __restrict__ keys) {
  __shared__ unsigned blocal, bbase;
  const int t = threadIdx.x;
  if (t == 0) blocal = 0;
  __syncthreads();
  const unsigned T = cnt[1];
  const int gi = blockIdx.x * 256 + t;
  float4 s4 = ((const float4*)scores)[gi];
  float sv[4] = {s4.x, s4.y, s4.z, s4.w};
  ull lk[4]; int nl = 0;
  #pragma unroll
  for (int k = 0; k < 4; ++k) {
    float s = sv[k];
    if (s <= 0.f) continue;
    unsigned bits = __float_as_uint(s);
    int idx = (int)(bits >> 16) - BIN0;
    if (idx > NBIN - 1) idx = NBIN - 1;
    if ((unsigned)idx < T) continue;
    unsigned r = (unsigned)(gi * 4 + k);
    lk[nl++] = ((ull)bits << 32) | (ull)(0xFFFFFFFFu - r);
  }
  unsigned lpos = nl ? atomicAdd(&blocal, (unsigned)nl) : 0u;
  __syncthreads();
  if (t == 0 && blocal) bbase = atomicAdd(&cnt[0], blocal);
  __syncthreads();
  if (nl) {
    unsigned base = bbase + lpos;
    for (int i = 0; i < nl; ++i)
      if (base + i < CAP) keys[base + i] = lk[i];
  }
}

__global__ __launch_bounds__(64) void rank_kernel(
    const float* __restrict__ x, const float* __restrict__ anchors,
    const unsigned* __restrict__ cnt, const ull* __restrict__ keys,
    ull* __restrict__ sorted, float4* __restrict__ cboxg) {
  __shared__ ull lk[MAXN];
  unsigned n = cnt[0]; if (n > CAP) n = CAP;
  const int t = threadIdx.x;
  for (unsigned i = t; i < n; i += 64) lk[i] = keys[i];
  __syncthreads();
  const unsigned i = blockIdx.x * 64 + t;
  if (i >= n) return;
  const ull ki = lk[i];
  unsigned rank = 0;
  #pragma unroll 4
  for (unsigned j = 0; j < n; ++j) rank += (lk[j] > ki) ? 1u : 0u;
  sorted[rank] = ki;
  unsigned r = 0xFFFFFFFFu - (unsigned)(ki & 0xFFFFFFFFull);
  const float* rp = x + (size_t)r * 85;
  float tx = rp[0], ty = rp[1], tw = rp[2], th = rp[3];
  const int a  = (int)(r % 5u);
  const int hw = (int)(r / 5u);
  const float wf = (float)(hw & 255);
  const float hf = (float)(hw >> 8);
  float sx = 1.f / (1.f + expf(-tx));
  float sy = 1.f / (1.f + expf(-ty));
  float xc = (sx + wf) / 256.f;
  float yc = (sy + hf) / 256.f;
  float bw = expf(tw) * anchors[2*a]     / 256.f;
  float bh = expf(th) * anchors[2*a + 1] / 256.f;
  float hwd = bw / 2.f, hhd = bh / 2.f;
  cboxg[rank] = make_float4(xc - hwd, yc - hhd, xc + hwd, yc + hhd);
}

__global__ __launch_bounds__(256) void adj_kernel(
    const unsigned* __restrict__ cnt, const float4* __restrict__ cboxg,
    ull* __restrict__ adj) {
  unsigned n = cnt[0]; if (n > CAP) n = CAP;
  const unsigned i = blockIdx.x;
  if (i >= n) return;
  const float4 bi = cboxg[i];
  const float areai = (bi.z - bi.x) * (bi.w - bi.y);
  const int t = threadIdx.x, wid = t >> 6, lane = t & 63;
  #pragma unroll
  for (int pass = 0; pass < 8; ++pass) {
    unsigned j = (unsigned)(pass * 256 + t);
    bool sup = false;
    if (j < n) {
      float4 bj = cboxg[j];
      float xx1 = fmaxf(bi.x, bj.x), yy1 = fmaxf(bi.y, bj.y);
      float xx2 = fminf(bi.z, bj.z), yy2 = fminf(bi.w, bj.w);
      float inter = fmaxf(xx2 - xx1, 0.f) * fmaxf(yy2 - yy1, 0.f);
      float areaj = (bj.z - bj.x) * (bj.w - bj.y);
      float uni = areai + areaj - inter;
      float iou = (uni > 0.f) ? (inter / uni) : 0.f;
      sup = iou > 0.5f;
    }
    ull m = __ballot(sup);
    if (lane == 0) adj[(size_t)i * ADJW + pass * 4 + wid] = m;
  }
}

__global__ __launch_bounds__(1024) void final_kernel(
    const float* __restrict__ x, const unsigned* __restrict__ cnt,
    const ull* __restrict__ sorted, const float4* __restrict__ cboxg,
    const ull* __restrict__ adjg, float* __restrict__ out) {
  __shared__ ull sk[MAXN];
  __shared__ ull adjc[ADJC_ROWS * ADJW];
  __shared__ int keptcc[MAX_OUT];
  __shared__ int kcls[MAX_OUT];
  __shared__ int knum;
  const int t = threadIdx.x;
  if (t == 0) knum = 0;
  unsigned n = cnt[0]; if (n > CAP) n = CAP;
  for (unsigned i = t; i < n; i += 1024) sk[i] = sorted[i];
  const unsigned ncache = (n < ADJC_ROWS ? n : ADJC_ROWS) * ADJW;
  for (unsigned i = t; i < ncache; i += 1024) adjc[i] = adjg[i];
  __syncthreads();
  if (t < 64) {
    const int lane = t;
    ull mask = 0ull;
    int nk = 0;
    ull rA = 0ull, rB = 0ull;
    if (lane < ADJW) {
      if (n > 0) rA = adjc[0 * ADJW + lane];
      if (n > 1) rB = (1 < ADJC_ROWS) ? adjc[1 * ADJW + lane]
                                      : adjg[1 * ADJW + lane];
    }
    for (unsigned cc = 0; cc < n; ++cc) {
      ull rC = 0ull;
      unsigned pcc = cc + 2;
      if (lane < ADJW && pcc < n)
        rC = (pcc < ADJC_ROWS) ? adjc[pcc * ADJW + lane]
                               : adjg[(size_t)pcc * ADJW + lane];
      const int w = (int)(cc >> 6);
      ull mw = (ull)__shfl((long long)mask, w, 64);
      bool sup = (mw >> (cc & 63u)) & 1ull;
      if (!sup) {
        mask |= rA;
        if (lane == 0) keptcc[nk] = (int)cc;
        ++nk;
        if (nk == MAX_OUT) break;
      }
      rA = rB; rB = rC;
    }
    if (lane == 0) knum = nk;
  }
  __syncthreads();
  const int kn = knum;
  {
    const int wv = t >> 6, lane = t & 63;
    for (int kidx = wv; kidx < kn; kidx += 16) {
      ull key = sk[keptcc[kidx]];
      unsigned r = 0xFFFFFFFFu - (unsigned)(key & 0xFFFFFFFFull);
      const float* rp = x + (size_t)r * 85;
      float l0 = rp[5 + lane];
      unsigned b0 = __float_as_uint(l0);
      b0 = (b0 & 0x80000000u) ? ~b0 : (b0 | 0x80000000u);
      ull kv = ((ull)b0 << 32) | (ull)(0xFFFFFFFFu - lane);
      if (lane < 16) {
        float l1 = rp[5 + 64 + lane];
        unsigned b1 = __float_as_uint(l1);
        b1 = (b1 & 0x80000000u) ? ~b1 : (b1 | 0x80000000u);
        ull kv1 = ((ull)b1 << 32) | (ull)(0xFFFFFFFFu - (64 + lane));
        if (kv1 > kv) kv = kv1;
      }
      #pragma unroll
      for (int d = 32; d >= 1; d >>= 1) {
        ull o = (ull)__shfl_xor((long long)kv, d, 64);
        if (o > kv) kv = o;
      }
      if (lane == 0)
        kcls[kidx] = (int)(0xFFFFFFFFu - (unsigned)(kv & 0xFFFFFFFFull));
    }
  }
  __syncthreads();
  if (t < MAX_OUT) {
    float conf = 0.f; float4 bb = make_float4(0.f, 0.f, 0.f, 0.f); float cf = -1.f;
    if (t < kn) {
      int cc = keptcc[t];
      ull key = sk[cc];
      conf = __uint_as_float((unsigned)(key >> 32));
      bb = cboxg[cc];
      cf = (float)kcls[t];
    }
    out[t] = conf;
    ((float4*)(out + 100))[t] = bb;
    out[500 + t] = cf;
  }
}

// ---------------------------------------------------------------------------
extern "C" void kernel_launch(void* const* d_in, const int* in_sizes, int n_in,
                              void* d_out, int out_size, void* d_ws, size_t ws_size,
                              hipStream_t stream) {
  const float* x       = (const float*)d_in[0];
  const float* anchors = (const float*)d_in[1];
  float* out = (float*)d_out;
  char* ws = (char*)d_ws;

  float*    scores = (float*)(ws + WS_SCORES);
  unsigned* part   = (unsigned*)(ws + WS_PART);
  unsigned* colsum = (unsigned*)(ws + WS_COLSUM);
  unsigned* cnt    = (unsigned*)(ws + WS_CNT);
  int*      keptg  = (int*)(ws + WS_KEPT);
  ull*      keys   = (ull*)(ws + WS_KEYS);
  ull*      sorted = (ull*)(ws + WS_SORT);
  float4*   cboxg  = (float4*)(ws + WS_CBOX);
  ull*      adj    = (ull*)(ws + WS_ADJ);

  void* args[] = {
    (void*)&x, (void*)&anchors, (void*)&out,
    (void*)&scores, (void*)&part, (void*)&colsum, (void*)&cnt,
    (void*)&keptg, (void*)&keys, (void*)&sorted, (void*)&cboxg, (void*)&adj
  };
  hipError_t e = hipLaunchCooperativeKernel(mega_kernel, dim3(MGRID), dim3(256),
                                            args, 0, stream);
  if (e != hipSuccess) {
    (void)hipGetLastError();   // clear sticky error, fall back to legacy path
    hipLaunchKernelGGL(decode_score, dim3(NROW / 256), dim3(256),
                       0, stream, x, scores);
    hipLaunchKernelGGL(hist_kernel, dim3(HIST_BLOCKS), dim3(1024),
                       0, stream, scores, part);
    hipLaunchKernelGGL(thresh_kernel, dim3(1), dim3(1024), 0, stream, part, cnt);
    hipLaunchKernelGGL(compact_kernel, dim3(NROW / 1024), dim3(256),
                       0, stream, scores, cnt, keys);
    hipLaunchKernelGGL(rank_kernel, dim3(MAXN / 64), dim3(64),
                       0, stream, x, anchors, cnt, keys, sorted, cboxg);
    hipLaunchKernelGGL(adj_kernel, dim3(MAXN), dim3(256),
                       0, stream, cnt, cboxg, adj);
    hipLaunchKernelGGL(final_kernel, dim3(1), dim3(1024), 0, stream,
                       x, cnt, sorted, cboxg, adj, out);
  }
}

// Round 5
// 234.953 us; speedup vs baseline: 2.6116x; 2.6116x over previous
//
#include <hip/hip_runtime.h>
#include <hip/hip_bf16.h>

#define NROW 327680            // 256*256*5
#define NCLS 80
#define K_TARGET 1024u
#define CAP 2048u              // == MAXN
#define MAXN 2048
#define MAX_OUT 100
#define NBIN 864               // score in (0.01,1): bits>>16 in [0x3C23, 0x3F80)
#define BIN0 0x3C23
#define HIST_BLOCKS 80
#define ADJW 32                // 2048 bits = 32 ull per adjacency row
#define ADJC_ROWS 128          // adjacency rows cached in LDS for the greedy scan

// ---------------- workspace layout (bytes) ----------------
#define WS_SCORES 0            // float[NROW]          1,310,720
#define WS_PART   1310720      // uint[80*864]           276,480
#define WS_CNT    1587200      // uint[16]                    64
#define WS_KEYS   1587264      // ull[MAXN]               16,384
#define WS_SORT   1603648      // ull[MAXN]               16,384
#define WS_CBOX   1620032      // float4[MAXN]            32,768
#define WS_ADJ    1652800      // ull[MAXN*ADJW]         524,288

typedef float f4v __attribute__((ext_vector_type(4)));
typedef f4v f4u __attribute__((aligned(4)));   // 4B-aligned float4 load
typedef unsigned long long ull;

// ---------------------------------------------------------------------------
// Kernel 1: scores only. R5 probe: R0 register-resident body VERBATIM
// (bit-identical scores), with __launch_bounds__(256,4) = 128-VGPR cap.
// Rationale: R4's mega spilled cl[80] at 68 VGPRs (scratch round trips,
// 8x slowdown) — which means R3's 102-VGPR cap may ALSO have spilled,
// spoiling the occupancy test. This config fits ~100 live values under 128
// with zero LDS -> 4 waves/SIMD (50% occ) with clean codegen.
// Discriminator: dur 35-50 => occupancy was the bottleneck (R3 spoiled);
// dur ~62 @ VGPR 100-128 / occ ~50 => memory-system cap confirmed, decode
// is at its floor under 4 tested structures.
// ---------------------------------------------------------------------------
__global__ __launch_bounds__(256, 4) void decode_score(
    const float* __restrict__ x, float* __restrict__ scores) {
  const int r = blockIdx.x * 256 + threadIdx.x;
  const float* rp = x + (size_t)r * 85;

  float conf_l = rp[4];
  float cl[80];
  #pragma unroll
  for (int c = 0; c < 20; ++c) {           // floats 5..84 = exactly 20 x vec4
    f4v t4 = *(const f4u*)(rp + 5 + 4 * c);
    cl[4*c+0] = t4.x; cl[4*c+1] = t4.y; cl[4*c+2] = t4.z; cl[4*c+3] = t4.w;
  }

  float m = cl[0];
  #pragma unroll
  for (int c = 1; c < NCLS; ++c) { float l = cl[c]; if (l > m) m = l; }
  float s = 0.f;
  #pragma unroll
  for (int c = 0; c < NCLS; ++c) s += expf(cl[c] - m);
  float conf = 1.f / (1.f + expf(-conf_l));
  float best = conf * (1.f / s);
  scores[r] = (best > 0.01f) ? best : 0.f;
}

// ---------------------------------------------------------------------------
// Kernel 2: per-block LDS histogram -> part[block][bin] (non-atomic global).
// ---------------------------------------------------------------------------
__global__ __launch_bounds__(1024) void hist_kernel(
    const float* __restrict__ scores, unsigned* __restrict__ part) {
  __shared__ unsigned h[NBIN];
  const int t = threadIdx.x;
  if (t < NBIN) h[t] = 0;
  __syncthreads();

  float4 s4 = ((const float4*)scores)[blockIdx.x * 1024 + t];
  float sv[4] = {s4.x, s4.y, s4.z, s4.w};
  #pragma unroll
  for (int k = 0; k < 4; ++k) {
    float s = sv[k];
    if (s > 0.f) {
      int idx = (int)(__float_as_uint(s) >> 16) - BIN0;
      if (idx > NBIN - 1) idx = NBIN - 1;
      atomicAdd(&h[idx], 1u);             // LDS atomic only
    }
  }
  __syncthreads();
  if (t < NBIN) part[blockIdx.x * NBIN + t] = h[t];
}

// ---------------------------------------------------------------------------
// Kernel 3: reduce part + suffix-scan -> threshold T (bit-identical semantics
// to R4-R8); zero-init cnt[0].
// ---------------------------------------------------------------------------
__global__ __launch_bounds__(1024) void thresh_kernel(
    const unsigned* __restrict__ part, unsigned* __restrict__ cnt) {
  __shared__ unsigned bufA[1024], bufB[1024];
  const int t = threadIdx.x;

  unsigned colsum = 0;
  if (t < NBIN) {
    unsigned a0 = 0, a1 = 0, a2 = 0, a3 = 0;
    #pragma unroll
    for (int b = 0; b < HIST_BLOCKS; b += 4) {
      a0 += part[(b + 0) * NBIN + t];
      a1 += part[(b + 1) * NBIN + t];
      a2 += part[(b + 2) * NBIN + t];
      a3 += part[(b + 3) * NBIN + t];
    }
    colsum = a0 + a1 + a2 + a3;
  }
  bufA[t] = colsum;
  __syncthreads();

  unsigned* src = bufA; unsigned* dst = bufB;
  for (int d = 1; d < 1024; d <<= 1) {
    unsigned val = src[t] + ((t + d < 1024) ? src[t + d] : 0u);
    dst[t] = val;
    __syncthreads();
    unsigned* tmp = src; src = dst; dst = tmp;
  }
  if (src[t] >= K_TARGET && (t == 1023 || src[t + 1] < K_TARGET)) {
    unsigned T = (unsigned)t;
    if (src[t] > CAP) T += 1;             // residual sfx[t+1] < K_TARGET <= CAP
    cnt[1] = T;
  }
  if (t == 0) {
    if (src[0] < K_TARGET) cnt[1] = 0;    // fewer than K positives: take all
    cnt[0] = 0;
  }
}

// ---------------------------------------------------------------------------
// Kernel 4: device-wide compact; one global atomic per block. n <= CAP
// guaranteed by the thresh bump rule; order normalized by the rank sort.
// ---------------------------------------------------------------------------
__global__ __launch_bounds__(256) void compact_kernel(
    const float* __restrict__ scores, unsigned* __restrict__ cnt,
    ull* __restrict__ keys) {
  __shared__ unsigned blocal, bbase;
  const int t = threadIdx.x;
  if (t == 0) blocal = 0;
  __syncthreads();

  const unsigned T = cnt[1];
  const int gi = blockIdx.x * 256 + t;
  float4 s4 = ((const float4*)scores)[gi];
  float sv[4] = {s4.x, s4.y, s4.z, s4.w};
  ull lk[4]; int nl = 0;
  #pragma unroll
  for (int k = 0; k < 4; ++k) {
    float s = sv[k];
    if (s <= 0.f) continue;
    unsigned bits = __float_as_uint(s);
    int idx = (int)(bits >> 16) - BIN0;
    if (idx > NBIN - 1) idx = NBIN - 1;
    if ((unsigned)idx < T) continue;
    unsigned r = (unsigned)(gi * 4 + k);
    lk[nl++] = ((ull)bits << 32) | (ull)(0xFFFFFFFFu - r);
  }
  unsigned lpos = nl ? atomicAdd(&blocal, (unsigned)nl) : 0u;
  __syncthreads();
  if (t == 0 && blocal) bbase = atomicAdd(&cnt[0], blocal);
  __syncthreads();
  if (nl) {
    unsigned base = bbase + lpos;
    for (int i = 0; i < nl; ++i)
      if (base + i < CAP) keys[base + i] = lk[i];
  }
}

// ---------------------------------------------------------------------------
// Kernel 5: rank-scatter sort (device-wide). rank_i = #{j : key_j > key_i};
// keys unique -> exact permutation, identical order to bitonic desc sort.
// Also decodes candidate boxes (exact reference expressions) into cboxg[rank].
// ---------------------------------------------------------------------------
__global__ __launch_bounds__(64) void rank_kernel(
    const float* __restrict__ x, const float* __restrict__ anchors,
    const unsigned* __restrict__ cnt, const ull* __restrict__ keys,
    ull* __restrict__ sorted, float4* __restrict__ cboxg) {
  __shared__ ull lk[MAXN];
  unsigned n = cnt[0]; if (n > CAP) n = CAP;
  const int t = threadIdx.x;
  for (unsigned i = t; i < n; i += 64) lk[i] = keys[i];
  __syncthreads();

  const unsigned i = blockIdx.x * 64 + t;
  if (i >= n) return;
  const ull ki = lk[i];
  unsigned rank = 0;
  #pragma unroll 4
  for (unsigned j = 0; j < n; ++j) rank += (lk[j] > ki) ? 1u : 0u;

  sorted[rank] = ki;

  unsigned r = 0xFFFFFFFFu - (unsigned)(ki & 0xFFFFFFFFull);
  const float* rp = x + (size_t)r * 85;
  float tx = rp[0], ty = rp[1], tw = rp[2], th = rp[3];
  const int a  = (int)(r % 5u);
  const int hw = (int)(r / 5u);
  const float wf = (float)(hw & 255);
  const float hf = (float)(hw >> 8);
  float sx = 1.f / (1.f + expf(-tx));
  float sy = 1.f / (1.f + expf(-ty));
  float xc = (sx + wf) / 256.f;
  float yc = (sy + hf) / 256.f;
  float bw = expf(tw) * anchors[2*a]     / 256.f;
  float bh = expf(th) * anchors[2*a + 1] / 256.f;
  float hwd = bw / 2.f, hhd = bh / 2.f;
  cboxg[rank] = make_float4(xc - hwd, yc - hhd, xc + hwd, yc + hhd);
}

// ---------------------------------------------------------------------------
// Kernel 6: adjacency bitmap, device-wide. adj[i] bit j = IoU(i,j) > 0.5,
// using the reference's exact division-based IoU expression.
// ---------------------------------------------------------------------------
__global__ __launch_bounds__(256) void adj_kernel(
    const unsigned* __restrict__ cnt, const float4* __restrict__ cboxg,
    ull* __restrict__ adj) {
  unsigned n = cnt[0]; if (n > CAP) n = CAP;
  const unsigned i = blockIdx.x;
  if (i >= n) return;
  const float4 bi = cboxg[i];
  const float areai = (bi.z - bi.x) * (bi.w - bi.y);
  const int t = threadIdx.x, wid = t >> 6, lane = t & 63;

  #pragma unroll
  for (int pass = 0; pass < 8; ++pass) {
    unsigned j = (unsigned)(pass * 256 + t);
    bool sup = false;
    if (j < n) {
      float4 bj = cboxg[j];
      float xx1 = fmaxf(bi.x, bj.x), yy1 = fmaxf(bi.y, bj.y);
      float xx2 = fminf(bi.z, bj.z), yy2 = fminf(bi.w, bj.w);
      float inter = fmaxf(xx2 - xx1, 0.f) * fmaxf(yy2 - yy1, 0.f);
      float areaj = (bj.z - bj.x) * (bj.w - bj.y);
      float uni = areai + areaj - inter;
      float iou = (uni > 0.f) ? (inter / uni) : 0.f;
      sup = iou > 0.5f;
    }
    ull m = __ballot(sup);
    if (lane == 0) adj[(size_t)i * ADJW + pass * 4 + wid] = m;
  }
}

// ---------------------------------------------------------------------------
// Kernel 7: greedy NMS as a bitmask scan (stateless per-lane: 1 ull mask
// word/lane) + class argmax + output.
// ---------------------------------------------------------------------------
__global__ __launch_bounds__(1024) void final_kernel(
    const float* __restrict__ x, const unsigned* __restrict__ cnt,
    const ull* __restrict__ sorted, const float4* __restrict__ cboxg,
    const ull* __restrict__ adjg, float* __restrict__ out) {
  __shared__ ull sk[MAXN];                  // 16 KB
  __shared__ ull adjc[ADJC_ROWS * ADJW];    // 32 KB (rows 0..127 cached)
  __shared__ int keptcc[MAX_OUT];
  __shared__ int kcls[MAX_OUT];
  __shared__ int knum;
  const int t = threadIdx.x;
  if (t == 0) knum = 0;

  unsigned n = cnt[0]; if (n > CAP) n = CAP;
  for (unsigned i = t; i < n; i += 1024) sk[i] = sorted[i];
  const unsigned ncache = (n < ADJC_ROWS ? n : ADJC_ROWS) * ADJW;
  for (unsigned i = t; i < ncache; i += 1024) adjc[i] = adjg[i];
  __syncthreads();

  // ---- greedy bitmask scan: wave 0; lane l (l<32) owns mask word l ----
  if (t < 64) {
    const int lane = t;
    ull mask = 0ull;
    int nk = 0;
    // prefetch ring, depth 2
    ull rA = 0ull, rB = 0ull;
    if (lane < ADJW) {
      if (n > 0) rA = adjc[0 * ADJW + lane];
      if (n > 1) rB = (1 < ADJC_ROWS) ? adjc[1 * ADJW + lane]
                                      : adjg[1 * ADJW + lane];
    }
    for (unsigned cc = 0; cc < n; ++cc) {
      ull rC = 0ull;
      unsigned pcc = cc + 2;
      if (lane < ADJW && pcc < n)
        rC = (pcc < ADJC_ROWS) ? adjc[pcc * ADJW + lane]
                               : adjg[(size_t)pcc * ADJW + lane];
      const int w = (int)(cc >> 6);
      ull mw = (ull)__shfl((long long)mask, w, 64);
      bool sup = (mw >> (cc & 63u)) & 1ull;
      if (!sup) {
        mask |= rA;                         // row cc (self bit harmless)
        if (lane == 0) keptcc[nk] = (int)cc;
        ++nk;
        if (nk == MAX_OUT) break;
      }
      rA = rB; rB = rC;
    }
    if (lane == 0) knum = nk;
  }
  __syncthreads();
  const int kn = knum;

  // ---- wave-parallel class argmax (R6-proven packing/tie-break) ----
  {
    const int wv = t >> 6, lane = t & 63;
    for (int kidx = wv; kidx < kn; kidx += 16) {
      ull key = sk[keptcc[kidx]];
      unsigned r = 0xFFFFFFFFu - (unsigned)(key & 0xFFFFFFFFull);
      const float* rp = x + (size_t)r * 85;
      float l0 = rp[5 + lane];
      unsigned b0 = __float_as_uint(l0);
      b0 = (b0 & 0x80000000u) ? ~b0 : (b0 | 0x80000000u);
      ull kv = ((ull)b0 << 32) | (ull)(0xFFFFFFFFu - lane);
      if (lane < 16) {
        float l1 = rp[5 + 64 + lane];
        unsigned b1 = __float_as_uint(l1);
        b1 = (b1 & 0x80000000u) ? ~b1 : (b1 | 0x80000000u);
        ull kv1 = ((ull)b1 << 32) | (ull)(0xFFFFFFFFu - (64 + lane));
        if (kv1 > kv) kv = kv1;
      }
      #pragma unroll
      for (int d = 32; d >= 1; d >>= 1) {
        ull o = (ull)__shfl_xor((long long)kv, d, 64);
        if (o > kv) kv = o;
      }
      if (lane == 0)
        kcls[kidx] = (int)(0xFFFFFFFFu - (unsigned)(kv & 0xFFFFFFFFull));
    }
  }
  __syncthreads();

  // ---- outputs: [0..99] conf, [100..499] boxes (100,4), [500..599] classes ----
  if (t < MAX_OUT) {
    float conf = 0.f; float4 bb = make_float4(0.f, 0.f, 0.f, 0.f); float cf = -1.f;
    if (t < kn) {
      int cc = keptcc[t];
      ull key = sk[cc];
      conf = __uint_as_float((unsigned)(key >> 32));
      bb = cboxg[cc];
      cf = (float)kcls[t];
    }
    out[t] = conf;
    ((float4*)(out + 100))[t] = bb;
    out[500 + t] = cf;
  }
}

// ---------------------------------------------------------------------------
extern "C" void kernel_launch(void* const* d_in, const int* in_sizes, int n_in,
                              void* d_out, int out_size, void* d_ws, size_t ws_size,
                              hipStream_t stream) {
  const float* x       = (const float*)d_in[0];
  const float* anchors = (const float*)d_in[1];
  float* out = (float*)d_out;
  char* ws = (char*)d_ws;

  float*    scores = (float*)(ws + WS_SCORES);
  unsigned* part   = (unsigned*)(ws + WS_PART);
  unsigned* cnt    = (unsigned*)(ws + WS_CNT);
  ull*      keys   = (ull*)(ws + WS_KEYS);
  ull*      sorted = (ull*)(ws + WS_SORT);
  float4*   cboxg  = (float4*)(ws + WS_CBOX);
  ull*      adj    = (ull*)(ws + WS_ADJ);

  hipLaunchKernelGGL(decode_score, dim3(NROW / 256), dim3(256),
                     0, stream, x, scores);
  hipLaunchKernelGGL(hist_kernel, dim3(HIST_BLOCKS), dim3(1024),
                     0, stream, scores, part);
  hipLaunchKernelGGL(thresh_kernel, dim3(1), dim3(1024), 0, stream, part, cnt);
  hipLaunchKernelGGL(compact_kernel, dim3(NROW / 1024), dim3(256),
                     0, stream, scores, cnt, keys);
  hipLaunchKernelGGL(rank_kernel, dim3(MAXN / 64), dim3(64),
                     0, stream, x, anchors, cnt, keys, sorted, cboxg);
  hipLaunchKernelGGL(adj_kernel, dim3(MAXN), dim3(256),
                     0, stream, cnt, cboxg, adj);
  hipLaunchKernelGGL(final_kernel, dim3(1), dim3(1024), 0, stream,
                     x, cnt, sorted, cboxg, adj, out);
}